// Round 1
// 888.120 us; speedup vs baseline: 1.1279x; 1.1279x over previous
//
#include <hip/hip_runtime.h>

#define NUM_PL 50000
#define NUM_TR 100000
#define NUM_AR 10000
#define NN     160000          // NUM_PL + NUM_TR + NUM_AR
#define HID    64
#define FEAT   128
#define E_PLTR 2000000
#define E_TRAR 100000
#define E_TOT  4200000         // 2*E_PLTR + 2*E_TRAR
#define OFF_TR 50000
#define OFF_AR 150000

#define BIN_CHUNK 8192
#define NBLK_BIN  513          // ceil(E_TOT / BIN_CHUNK)
#define NBUCK     625          // NN / 256 (exact)
#define TABW      626          // NBUCK + 1
#define PKD_CAP   (NBLK_BIN * BIN_CHUNK)

// edge id -> (src,dst) global node ids, matching the reference concatenation
__device__ __forceinline__ void edge_sd(
    int e, const int* __restrict__ pls, const int* __restrict__ pld,
    const int* __restrict__ tas, const int* __restrict__ tad, int& s, int& d) {
  if (e < E_PLTR)                   { s = pls[e];               d = pld[e] + OFF_TR; }
  else if (e < 2 * E_PLTR)          { int i = e - E_PLTR;
                                      s = pld[i] + OFF_TR;      d = pls[i]; }
  else if (e < 2 * E_PLTR + E_TRAR) { int i = e - 2 * E_PLTR;
                                      s = tas[i] + OFF_TR;      d = tad[i] + OFF_AR; }
  else                              { int i = e - 2 * E_PLTR - E_TRAR;
                                      s = tad[i] + OFF_AR;      d = tas[i] + OFF_TR; }
}

// ---------------------------------------------------------------------------
// x[pl] = playlist_emb + type_emb[0];  x[ar] = artist_emb + type_emb[2]
// ---------------------------------------------------------------------------
__global__ __launch_bounds__(256) void k_init_emb(
    const float* __restrict__ pl_emb, const float* __restrict__ ar_emb,
    const float* __restrict__ type_emb, float* __restrict__ x) {
  int tid = blockIdx.x * 256 + threadIdx.x;
  int f = tid & (HID - 1);
  if (tid < NUM_PL * HID) {
    x[tid] = pl_emb[tid] + type_emb[f];
  } else {
    int idx = tid - NUM_PL * HID;
    if (idx < NUM_AR * HID)
      x[OFF_AR * HID + idx] = ar_emb[idx] + type_emb[2 * HID + f];
  }
}

// ---------------------------------------------------------------------------
// x[tr] = track_x @ W^T + b + type_emb[1]   (wave: 8 rows, lane = out feat)
// ---------------------------------------------------------------------------
__global__ __launch_bounds__(256) void k_track_lin(
    const float* __restrict__ tx, const float* __restrict__ W,
    const float* __restrict__ b, const float* __restrict__ type_emb,
    float* __restrict__ x) {
  __shared__ float WS[FEAT * HID];   // WS[k*64 + j] = W[j*128 + k]
  __shared__ float bs[HID];
  int t = threadIdx.x;
  for (int idx = t; idx < HID * FEAT; idx += 256) {
    int j = idx >> 7, k = idx & (FEAT - 1);
    WS[k * HID + j] = W[idx];
  }
  if (t < HID) bs[t] = b[t] + type_emb[HID + t];
  __syncthreads();

  int j  = t & 63;
  int wv = __builtin_amdgcn_readfirstlane(t >> 6);
  int row0 = blockIdx.x * 32 + wv * 8;
  const float* xr = tx + (size_t)row0 * FEAT;

  float acc[8] = {0.f, 0.f, 0.f, 0.f, 0.f, 0.f, 0.f, 0.f};
#pragma unroll 4
  for (int k = 0; k < FEAT; ++k) {
    float w = WS[k * HID + j];
#pragma unroll
    for (int r = 0; r < 8; ++r)
      acc[r] += xr[r * FEAT + k] * w;
  }
#pragma unroll
  for (int r = 0; r < 8; ++r)
    x[(OFF_TR + row0 + r) * HID + j] = acc[r] + bs[j];
}

// ---------------------------------------------------------------------------
// k_bin: each block takes BIN_CHUNK edges, groups them by dst bucket (d>>8)
// inside LDS, writes packed entries (d_off<<18 | s) to its OWN contiguous
// region pkd[e0 .. e0+cnt) -- dense block-private writes, zero cross-XCD
// line sharing. tab[blk*TABW + b] = absolute slice start.
// All derived indices clamped: worst case = wrong data, never OOB.
// ---------------------------------------------------------------------------
__global__ __launch_bounds__(256) void k_bin(
    const int* __restrict__ pls, const int* __restrict__ pld,
    const int* __restrict__ tas, const int* __restrict__ tad,
    int* __restrict__ pkd, int* __restrict__ tab) {
  __shared__ int hist[TABW];     // counts, then reused as write cursors
  __shared__ int offs[TABW];     // exclusive scan
  __shared__ int scanbuf[256];
  int t = threadIdx.x;
  int blk = blockIdx.x;
  int e0 = blk * BIN_CHUNK;
  int e1 = e0 + BIN_CHUNK; if (e1 > E_TOT) e1 = E_TOT;

  for (int i = t; i < TABW; i += 256) hist[i] = 0;
  __syncthreads();

  for (int e = e0 + t; e < e1; e += 256) {
    int s, d; edge_sd(e, pls, pld, tas, tad, s, d);
    int b = min(max(d >> 8, 0), NBUCK - 1);
    atomicAdd(&hist[b], 1);
  }
  __syncthreads();

  // exclusive scan of hist[0..624] -> offs[0..625]
  int i0 = 3 * t, i1 = 3 * t + 1, i2 = 3 * t + 2;
  int h0 = (i0 < NBUCK) ? hist[i0] : 0;
  int h1 = (i1 < NBUCK) ? hist[i1] : 0;
  int h2 = (i2 < NBUCK) ? hist[i2] : 0;
  int lsum = h0 + h1 + h2;
  scanbuf[t] = lsum;
  __syncthreads();
  int incl = lsum;
#pragma unroll
  for (int off = 1; off < 256; off <<= 1) {
    int add = (t >= off) ? scanbuf[t - off] : 0;
    __syncthreads();
    incl += add;
    scanbuf[t] = incl;
    __syncthreads();
  }
  int base = incl - lsum;
  if (i0 < TABW) offs[i0] = base;
  if (i1 < TABW) offs[i1] = base + h0;
  if (i2 < TABW) offs[i2] = base + h0 + h1;
  __syncthreads();

  for (int i = t; i < TABW; i += 256) tab[blk * TABW + i] = e0 + offs[i];
  for (int i = t; i < NBUCK; i += 256) hist[i] = offs[i];  // cursors
  __syncthreads();

  for (int e = e0 + t; e < e1; e += 256) {
    int s, d; edge_sd(e, pls, pld, tas, tad, s, d);
    int b = min(max(d >> 8, 0), NBUCK - 1);
    int pos = atomicAdd(&hist[b], 1);
    int idx = min(max(e0 + pos, 0), PKD_CAP - 1);   // clamp (no-op if correct)
    pkd[idx] = ((d & 255) << 18) | s;
  }
}

// ---------------------------------------------------------------------------
// k_btot: bucket b total edge count = sum over bin-blocks of slice sizes.
// Replaces the 4.2M global-atomic k_deg_int (which write-through'd 131 MB).
// 3 blocks, coalesced reads of tab (1.3 MB), no atomics.
// ---------------------------------------------------------------------------
__global__ __launch_bounds__(256) void k_btot(
    const int* __restrict__ tab, int* __restrict__ btot) {
  int b = blockIdx.x * 256 + threadIdx.x;
  if (b >= NBUCK) return;
  int sum = 0;
#pragma unroll 8
  for (int blk = 0; blk < NBLK_BIN; ++blk)
    sum += tab[blk * TABW + b + 1] - tab[blk * TABW + b];
  btot[b] = sum;
}

// ---------------------------------------------------------------------------
// k_bscan: single block, exclusive scan of the 625 bucket totals in place
// -> absolute bucket start offsets into col.
// ---------------------------------------------------------------------------
__global__ __launch_bounds__(1024) void k_bscan(int* __restrict__ btot) {
  __shared__ int s[1024];
  int t = threadIdx.x;
  int val = (t < NBUCK) ? btot[t] : 0;
  s[t] = val;
  __syncthreads();
  int incl = val;
#pragma unroll
  for (int off = 1; off < 1024; off <<= 1) {
    int add = (t >= off) ? s[t - off] : 0;
    __syncthreads();
    incl += add;
    s[t] = incl;
    __syncthreads();
  }
  if (t < NBUCK) btot[t] = incl - val;  // exclusive
}

// ---------------------------------------------------------------------------
// k_fill3: one WG per 256-node bucket.
// Pass 1: walk the bucket's 513 pkd slices, count per-node degrees in LDS
//         (LDS atomics only), scan -> rowptr[b*256 + t] = bstart + excl.
// Pass 2: walk slices again, write col densely via LDS cursors.
// Replaces k_deg_int + 3-kernel global scan + k_fill2. No global atomics.
// All derived indices clamped: worst case = wrong data, never OOB.
// ---------------------------------------------------------------------------
__global__ __launch_bounds__(256) void k_fill3(
    const int* __restrict__ tab, const int* __restrict__ pkd,
    const int* __restrict__ btot, int* __restrict__ rowptr,
    int* __restrict__ col) {
  __shared__ int cnt[256];       // counts, then absolute write cursors
  __shared__ int scanbuf[256];
  int t = threadIdx.x;
  int b = blockIdx.x;
  cnt[t] = 0;
  __syncthreads();

  // pass 1: per-node degree counts
  for (int blk = t; blk < NBLK_BIN; blk += 256) {
    int s0 = tab[blk * TABW + b];
    int s1 = tab[blk * TABW + b + 1];
    s0 = min(max(s0, 0), PKD_CAP);
    s1 = min(max(s1, s0), PKD_CAP);
    for (int i = s0; i < s1; ++i) {
      int doff = (pkd[i] >> 18) & 255;
      atomicAdd(&cnt[doff], 1);
    }
  }
  __syncthreads();

  // exclusive scan of cnt -> per-node offsets within the bucket
  int val = cnt[t];
  scanbuf[t] = val;
  __syncthreads();
  int incl = val;
#pragma unroll
  for (int off = 1; off < 256; off <<= 1) {
    int add = (t >= off) ? scanbuf[t - off] : 0;
    __syncthreads();
    incl += add;
    scanbuf[t] = incl;
    __syncthreads();
  }
  int rp = btot[b] + incl - val;     // absolute CSR row start
  rowptr[(b << 8) + t] = rp;
  if (b == NBUCK - 1 && t == 255) rowptr[NN] = E_TOT;
  __syncthreads();                   // all reads of cnt (val) done
  cnt[t] = rp;                       // cursor
  __syncthreads();

  // pass 2: fill col
  for (int blk = t; blk < NBLK_BIN; blk += 256) {
    int s0 = tab[blk * TABW + b];
    int s1 = tab[blk * TABW + b + 1];
    s0 = min(max(s0, 0), PKD_CAP);
    s1 = min(max(s1, s0), PKD_CAP);
    for (int i = s0; i < s1; ++i) {
      int pk = pkd[i];
      int doff = (pk >> 18) & 255;
      int pos = atomicAdd(&cnt[doff], 1);
      pos = min(max(pos, 0), E_TOT - 1);            // clamp (no-op if correct)
      col[pos] = pk & 0x3FFFF;
    }
  }
}

// ---------------------------------------------------------------------------
// gather: agg[n] = (1/deg) * sum over in-neighbors of x[src]
// one wave per node; lane = (slot r = lane>>4, float4 col c = lane&15);
// 16 edges per wave-iter -> 4 independent float4 loads in flight per lane.
// ---------------------------------------------------------------------------
__global__ __launch_bounds__(256) void k_gather(
    const int* __restrict__ rowptr, const int* __restrict__ col,
    const float* __restrict__ x, float* __restrict__ agg) {
  int t = threadIdx.x;
  int lane = t & 63;
  int wv = t >> 6;
  int n = blockIdx.x * 4 + wv;
  int rp0 = rowptr[n], rp1 = rowptr[n + 1];
  int r = lane >> 4;          // neighbor slot 0..3
  int c = lane & 15;          // float4 column 0..15
  const float4* x4 = (const float4*)x;

  float4 a0 = {0.f, 0.f, 0.f, 0.f};
  float4 a1 = {0.f, 0.f, 0.f, 0.f};
  float4 a2 = {0.f, 0.f, 0.f, 0.f};
  float4 a3 = {0.f, 0.f, 0.f, 0.f};
  int base = rp0;
  for (; base + 16 <= rp1; base += 16) {
    int s0 = col[base + r];
    int s1 = col[base + 4 + r];
    int s2 = col[base + 8 + r];
    int s3 = col[base + 12 + r];
    float4 v0 = x4[(size_t)s0 * 16 + c];
    float4 v1 = x4[(size_t)s1 * 16 + c];
    float4 v2 = x4[(size_t)s2 * 16 + c];
    float4 v3 = x4[(size_t)s3 * 16 + c];
    a0.x += v0.x; a0.y += v0.y; a0.z += v0.z; a0.w += v0.w;
    a1.x += v1.x; a1.y += v1.y; a1.z += v1.z; a1.w += v1.w;
    a2.x += v2.x; a2.y += v2.y; a2.z += v2.z; a2.w += v2.w;
    a3.x += v3.x; a3.y += v3.y; a3.z += v3.z; a3.w += v3.w;
  }
  if (base + 4 <= rp1) {
    int s0 = col[base + r];
    float4 v0 = x4[(size_t)s0 * 16 + c];
    a0.x += v0.x; a0.y += v0.y; a0.z += v0.z; a0.w += v0.w;
    base += 4;
  }
  if (base + 4 <= rp1) {
    int s1 = col[base + r];
    float4 v1 = x4[(size_t)s1 * 16 + c];
    a1.x += v1.x; a1.y += v1.y; a1.z += v1.z; a1.w += v1.w;
    base += 4;
  }
  if (base + 4 <= rp1) {
    int s2 = col[base + r];
    float4 v2 = x4[(size_t)s2 * 16 + c];
    a2.x += v2.x; a2.y += v2.y; a2.z += v2.z; a2.w += v2.w;
    base += 4;
  }
  if (base + r < rp1) {
    int s3 = col[base + r];
    float4 v3 = x4[(size_t)s3 * 16 + c];
    a3.x += v3.x; a3.y += v3.y; a3.z += v3.z; a3.w += v3.w;
  }
  float4 a;
  a.x = (a0.x + a1.x) + (a2.x + a3.x);
  a.y = (a0.y + a1.y) + (a2.y + a3.y);
  a.z = (a0.z + a1.z) + (a2.z + a3.z);
  a.w = (a0.w + a1.w) + (a2.w + a3.w);
  a.x += __shfl_xor(a.x, 16); a.y += __shfl_xor(a.y, 16);
  a.z += __shfl_xor(a.z, 16); a.w += __shfl_xor(a.w, 16);
  a.x += __shfl_xor(a.x, 32); a.y += __shfl_xor(a.y, 32);
  a.z += __shfl_xor(a.z, 32); a.w += __shfl_xor(a.w, 32);
  if (r == 0) {
    float id = 1.0f / (float)max(rp1 - rp0, 1);
    float4 o;
    o.x = a.x * id; o.y = a.y * id; o.z = a.z * id; o.w = a.w * id;
    ((float4*)agg)[(size_t)n * 16 + c] = o;
  }
}

// ---------------------------------------------------------------------------
// x = relu(agg @ Wl^T + bl + x @ Wr^T)   (agg already mean'd); in-place x
// ---------------------------------------------------------------------------
__global__ __launch_bounds__(256) void k_update(
    const float* __restrict__ agg,
    const float* __restrict__ Wl, const float* __restrict__ bl,
    const float* __restrict__ Wr, float* x) {
  __shared__ float WlS[HID * HID];   // [k][j]
  __shared__ float WrS[HID * HID];
  __shared__ float bs[HID];
  int t = threadIdx.x;
  for (int idx = t; idx < HID * HID; idx += 256) {
    int j = idx >> 6, k = idx & 63;
    WlS[k * HID + j] = Wl[idx];
    WrS[k * HID + j] = Wr[idx];
  }
  if (t < HID) bs[t] = bl[t];
  __syncthreads();

  int j  = t & 63;
  int wv = __builtin_amdgcn_readfirstlane(t >> 6);
  int n0 = blockIdx.x * 32 + wv * 8;
  const float* ar = agg + (size_t)n0 * HID;
  const float* xr = x + (size_t)n0 * HID;

  float accA[8] = {0.f, 0.f, 0.f, 0.f, 0.f, 0.f, 0.f, 0.f};
  float accX[8] = {0.f, 0.f, 0.f, 0.f, 0.f, 0.f, 0.f, 0.f};
#pragma unroll 4
  for (int k = 0; k < HID; ++k) {
    float wl = WlS[k * HID + j];
    float wr = WrS[k * HID + j];
#pragma unroll
    for (int r = 0; r < 8; ++r) {
      accA[r] += ar[r * HID + k] * wl;
      accX[r] += xr[r * HID + k] * wr;
    }
  }
#pragma unroll
  for (int r = 0; r < 8; ++r) {
    float v = accA[r] + accX[r] + bs[j];
    x[(n0 + r) * HID + j] = fmaxf(v, 0.f);
  }
}

// ---------------------------------------------------------------------------
extern "C" void kernel_launch(void* const* d_in, const int* in_sizes, int n_in,
                              void* d_out, int out_size, void* d_ws, size_t ws_size,
                              hipStream_t stream) {
  const float* track_x  = (const float*)d_in[0];
  const int*   pl_tr_s  = (const int*)d_in[1];
  const int*   pl_tr_d  = (const int*)d_in[2];
  const int*   tr_ar_s  = (const int*)d_in[3];
  const int*   tr_ar_d  = (const int*)d_in[4];
  const float* pl_emb   = (const float*)d_in[5];
  const float* ar_emb   = (const float*)d_in[6];
  const float* track_W  = (const float*)d_in[7];
  const float* track_b  = (const float*)d_in[8];
  const float* type_emb = (const float*)d_in[9];
  const float* conv_Wl  = (const float*)d_in[10];
  const float* conv_bl  = (const float*)d_in[11];
  const float* conv_Wr  = (const float*)d_in[12];

  float* x = (float*)d_out;                      // node state (NN*64)

  // workspace: agg ALIASES [pkd|tab] -- pkd/tab are dead once k_fill3 has
  // produced rowptr+col; agg is first written by k_gather (stream-ordered
  // after). Total: 40.96 (agg region, covers pkd 16.81 + tab 1.29) +
  // col 16.8 + rowptr 0.64 + btot 4KB = ~58.4 MB (< prior proven 59.1 MB).
  char* w = (char*)d_ws;
  float* agg    = (float*)w;
  int*   pkd    = (int*)w;
  int*   tab    = (int*)(w + (size_t)PKD_CAP * 4);
  w += (size_t)NN * HID * 4;
  int*   col    = (int*)w;    w += (size_t)E_TOT * 4;
  int*   rowptr = (int*)w;    w += (size_t)(NN + 1) * 4;
  int*   btot   = (int*)w;    // NBUCK ints

  k_init_emb<<<(NUM_PL + NUM_AR) * HID / 256, 256, 0, stream>>>(
      pl_emb, ar_emb, type_emb, x);
  k_track_lin<<<NUM_TR / 32, 256, 0, stream>>>(
      track_x, track_W, track_b, type_emb, x);

  // CSR build: bin -> bucket totals -> bucket scan -> count+scan+fill
  // (no global atomics, no 160K-wide degree pass)
  k_bin<<<NBLK_BIN, 256, 0, stream>>>(
      pl_tr_s, pl_tr_d, tr_ar_s, tr_ar_d, pkd, tab);
  k_btot<<<(NBUCK + 255) / 256, 256, 0, stream>>>(tab, btot);
  k_bscan<<<1, 1024, 0, stream>>>(btot);
  k_fill3<<<NBUCK, 256, 0, stream>>>(tab, pkd, btot, rowptr, col);

  for (int l = 0; l < 2; ++l) {
    k_gather<<<NN / 4, 256, 0, stream>>>(rowptr, col, x, agg);
    k_update<<<NN / 32, 256, 0, stream>>>(
        agg, conv_Wl + l * HID * HID, conv_bl + l * HID,
        conv_Wr + l * HID * HID, x);
  }
}

// Round 2
// 852.295 us; speedup vs baseline: 1.1753x; 1.0420x over previous
//
#include <hip/hip_runtime.h>

#define NUM_PL 50000
#define NUM_TR 100000
#define NUM_AR 10000
#define NN     160000          // NUM_PL + NUM_TR + NUM_AR
#define HID    64
#define FEAT   128
#define E_PLTR 2000000
#define E_TRAR 100000
#define E_TOT  4200000         // 2*E_PLTR + 2*E_TRAR
#define OFF_TR 50000
#define OFF_AR 150000

#define BIN_CHUNK 8192
#define NBLK_BIN  513          // ceil(E_TOT / BIN_CHUNK)
#define NBUCK     625          // NN / 256 (exact)
#define TABW      626          // NBUCK + 1
#define PKD_CAP   (NBLK_BIN * BIN_CHUNK)

// edge id -> (src,dst) global node ids, matching the reference concatenation
__device__ __forceinline__ void edge_sd(
    int e, const int* __restrict__ pls, const int* __restrict__ pld,
    const int* __restrict__ tas, const int* __restrict__ tad, int& s, int& d) {
  if (e < E_PLTR)                   { s = pls[e];               d = pld[e] + OFF_TR; }
  else if (e < 2 * E_PLTR)          { int i = e - E_PLTR;
                                      s = pld[i] + OFF_TR;      d = pls[i]; }
  else if (e < 2 * E_PLTR + E_TRAR) { int i = e - 2 * E_PLTR;
                                      s = tas[i] + OFF_TR;      d = tad[i] + OFF_AR; }
  else                              { int i = e - 2 * E_PLTR - E_TRAR;
                                      s = tad[i] + OFF_AR;      d = tas[i] + OFF_TR; }
}

// ---------------------------------------------------------------------------
// x[pl] = playlist_emb + type_emb[0];  x[ar] = artist_emb + type_emb[2]
// ---------------------------------------------------------------------------
__global__ __launch_bounds__(256) void k_init_emb(
    const float* __restrict__ pl_emb, const float* __restrict__ ar_emb,
    const float* __restrict__ type_emb, float* __restrict__ x) {
  int tid = blockIdx.x * 256 + threadIdx.x;
  int f = tid & (HID - 1);
  if (tid < NUM_PL * HID) {
    x[tid] = pl_emb[tid] + type_emb[f];
  } else {
    int idx = tid - NUM_PL * HID;
    if (idx < NUM_AR * HID)
      x[OFF_AR * HID + idx] = ar_emb[idx] + type_emb[2 * HID + f];
  }
}

// ---------------------------------------------------------------------------
// x[tr] = track_x @ W^T + b + type_emb[1]   (wave: 8 rows, lane = out feat)
// ---------------------------------------------------------------------------
__global__ __launch_bounds__(256) void k_track_lin(
    const float* __restrict__ tx, const float* __restrict__ W,
    const float* __restrict__ b, const float* __restrict__ type_emb,
    float* __restrict__ x) {
  __shared__ float WS[FEAT * HID];   // WS[k*64 + j] = W[j*128 + k]
  __shared__ float bs[HID];
  int t = threadIdx.x;
  for (int idx = t; idx < HID * FEAT; idx += 256) {
    int j = idx >> 7, k = idx & (FEAT - 1);
    WS[k * HID + j] = W[idx];
  }
  if (t < HID) bs[t] = b[t] + type_emb[HID + t];
  __syncthreads();

  int j  = t & 63;
  int wv = __builtin_amdgcn_readfirstlane(t >> 6);
  int row0 = blockIdx.x * 32 + wv * 8;
  const float* xr = tx + (size_t)row0 * FEAT;

  float acc[8] = {0.f, 0.f, 0.f, 0.f, 0.f, 0.f, 0.f, 0.f};
#pragma unroll 4
  for (int k = 0; k < FEAT; ++k) {
    float w = WS[k * HID + j];
#pragma unroll
    for (int r = 0; r < 8; ++r)
      acc[r] += xr[r * FEAT + k] * w;
  }
#pragma unroll
  for (int r = 0; r < 8; ++r)
    x[(OFF_TR + row0 + r) * HID + j] = acc[r] + bs[j];
}

// ---------------------------------------------------------------------------
// k_bin: each block takes BIN_CHUNK edges, groups them by dst bucket (d>>8)
// inside LDS, writes packed entries (d_off<<18 | s) to its OWN contiguous
// region pkd[e0 .. e0+cnt). tab[blk*TABW + b] = absolute slice start.
// All derived indices clamped: worst case = wrong data, never OOB.
// ---------------------------------------------------------------------------
__global__ __launch_bounds__(256) void k_bin(
    const int* __restrict__ pls, const int* __restrict__ pld,
    const int* __restrict__ tas, const int* __restrict__ tad,
    int* __restrict__ pkd, int* __restrict__ tab) {
  __shared__ int hist[TABW];     // counts, then reused as write cursors
  __shared__ int offs[TABW];     // exclusive scan
  __shared__ int scanbuf[256];
  int t = threadIdx.x;
  int blk = blockIdx.x;
  int e0 = blk * BIN_CHUNK;
  int e1 = e0 + BIN_CHUNK; if (e1 > E_TOT) e1 = E_TOT;

  for (int i = t; i < TABW; i += 256) hist[i] = 0;
  __syncthreads();

  for (int e = e0 + t; e < e1; e += 256) {
    int s, d; edge_sd(e, pls, pld, tas, tad, s, d);
    int b = min(max(d >> 8, 0), NBUCK - 1);
    atomicAdd(&hist[b], 1);
  }
  __syncthreads();

  // exclusive scan of hist[0..624] -> offs[0..625]
  int i0 = 3 * t, i1 = 3 * t + 1, i2 = 3 * t + 2;
  int h0 = (i0 < NBUCK) ? hist[i0] : 0;
  int h1 = (i1 < NBUCK) ? hist[i1] : 0;
  int h2 = (i2 < NBUCK) ? hist[i2] : 0;
  int lsum = h0 + h1 + h2;
  scanbuf[t] = lsum;
  __syncthreads();
  int incl = lsum;
#pragma unroll
  for (int off = 1; off < 256; off <<= 1) {
    int add = (t >= off) ? scanbuf[t - off] : 0;
    __syncthreads();
    incl += add;
    scanbuf[t] = incl;
    __syncthreads();
  }
  int base = incl - lsum;
  if (i0 < TABW) offs[i0] = base;
  if (i1 < TABW) offs[i1] = base + h0;
  if (i2 < TABW) offs[i2] = base + h0 + h1;
  __syncthreads();

  for (int i = t; i < TABW; i += 256) tab[blk * TABW + i] = e0 + offs[i];
  for (int i = t; i < NBUCK; i += 256) hist[i] = offs[i];  // cursors
  __syncthreads();

  for (int e = e0 + t; e < e1; e += 256) {
    int s, d; edge_sd(e, pls, pld, tas, tad, s, d);
    int b = min(max(d >> 8, 0), NBUCK - 1);
    int pos = atomicAdd(&hist[b], 1);
    int idx = min(max(e0 + pos, 0), PKD_CAP - 1);   // clamp (no-op if correct)
    pkd[idx] = ((d & 255) << 18) | s;
  }
}

// ---------------------------------------------------------------------------
// k_btot: bucket b total edge count = sum over bin-blocks of slice sizes.
// ---------------------------------------------------------------------------
__global__ __launch_bounds__(256) void k_btot(
    const int* __restrict__ tab, int* __restrict__ btot) {
  int b = blockIdx.x * 256 + threadIdx.x;
  if (b >= NBUCK) return;
  int sum = 0;
#pragma unroll 8
  for (int blk = 0; blk < NBLK_BIN; ++blk)
    sum += tab[blk * TABW + b + 1] - tab[blk * TABW + b];
  btot[b] = sum;
}

// ---------------------------------------------------------------------------
// k_bscan: single block, exclusive scan of the 625 bucket totals in place
// ---------------------------------------------------------------------------
__global__ __launch_bounds__(1024) void k_bscan(int* __restrict__ btot) {
  __shared__ int s[1024];
  int t = threadIdx.x;
  int val = (t < NBUCK) ? btot[t] : 0;
  s[t] = val;
  __syncthreads();
  int incl = val;
#pragma unroll
  for (int off = 1; off < 1024; off <<= 1) {
    int add = (t >= off) ? s[t - off] : 0;
    __syncthreads();
    incl += add;
    s[t] = incl;
    __syncthreads();
  }
  if (t < NBUCK) btot[t] = incl - val;  // exclusive
}

// ---------------------------------------------------------------------------
// k_fill3: one WG per 256-node bucket.
// Pass 1: count per-node degrees in LDS, scan -> rowptr.
// Pass 2: write col densely via LDS cursors. No global atomics.
// ---------------------------------------------------------------------------
__global__ __launch_bounds__(256) void k_fill3(
    const int* __restrict__ tab, const int* __restrict__ pkd,
    const int* __restrict__ btot, int* __restrict__ rowptr,
    int* __restrict__ col) {
  __shared__ int cnt[256];       // counts, then absolute write cursors
  __shared__ int scanbuf[256];
  int t = threadIdx.x;
  int b = blockIdx.x;
  cnt[t] = 0;
  __syncthreads();

  // pass 1: per-node degree counts
  for (int blk = t; blk < NBLK_BIN; blk += 256) {
    int s0 = tab[blk * TABW + b];
    int s1 = tab[blk * TABW + b + 1];
    s0 = min(max(s0, 0), PKD_CAP);
    s1 = min(max(s1, s0), PKD_CAP);
    for (int i = s0; i < s1; ++i) {
      int doff = (pkd[i] >> 18) & 255;
      atomicAdd(&cnt[doff], 1);
    }
  }
  __syncthreads();

  // exclusive scan of cnt -> per-node offsets within the bucket
  int val = cnt[t];
  scanbuf[t] = val;
  __syncthreads();
  int incl = val;
#pragma unroll
  for (int off = 1; off < 256; off <<= 1) {
    int add = (t >= off) ? scanbuf[t - off] : 0;
    __syncthreads();
    incl += add;
    scanbuf[t] = incl;
    __syncthreads();
  }
  int rp = btot[b] + incl - val;     // absolute CSR row start
  rowptr[(b << 8) + t] = rp;
  if (b == NBUCK - 1 && t == 255) rowptr[NN] = E_TOT;
  __syncthreads();                   // all reads of cnt (val) done
  cnt[t] = rp;                       // cursor
  __syncthreads();

  // pass 2: fill col
  for (int blk = t; blk < NBLK_BIN; blk += 256) {
    int s0 = tab[blk * TABW + b];
    int s1 = tab[blk * TABW + b + 1];
    s0 = min(max(s0, 0), PKD_CAP);
    s1 = min(max(s1, s0), PKD_CAP);
    for (int i = s0; i < s1; ++i) {
      int pk = pkd[i];
      int doff = (pk >> 18) & 255;
      int pos = atomicAdd(&cnt[doff], 1);
      pos = min(max(pos, 0), E_TOT - 1);            // clamp (no-op if correct)
      col[pos] = pk & 0x3FFFF;
    }
  }
}

// ---------------------------------------------------------------------------
// FUSED gather + SAGE update:
//   xn[n] = relu( (mean_{s in N(n)} xo[s]) @ Wl^T + bl + xo[n] @ Wr^T )
// 512 threads = 8 waves; 4 nodes per wave (32/block). Wl/Wr staged in LDS
// (transposed) once per block. Per node: wave gathers into registers
// (16 edges/iter, 4 independent load chains), shfl-reduces, parks the mean'd
// agg row + root row in a WAVE-PRIVATE 512B LDS slot (no barrier: single
// instruction stream per wave), then all 64 lanes compute one output feature
// each from LDS broadcasts and store a coalesced 256B row.
// Update VALU work hides under gather memory stalls (VALUBusy was 31%).
// Reads xo, writes xn (ping-pong) -- no in-place hazard.
// ---------------------------------------------------------------------------
__global__ __launch_bounds__(512, 8) void k_gather_update(
    const int* __restrict__ rowptr, const int* __restrict__ col,
    const float* __restrict__ xo,
    const float* __restrict__ Wl, const float* __restrict__ bl,
    const float* __restrict__ Wr,
    float* __restrict__ xn) {
  __shared__ float WlS[HID * HID];   // WlS[k*64+j] = Wl[j*64+k]
  __shared__ float WrS[HID * HID];
  __shared__ float bs[HID];
  __shared__ __align__(16) float rowS[8][2 * HID];  // per wave: agg | root
  int t = threadIdx.x;
  for (int idx = t; idx < HID * HID; idx += 512) {
    int j = idx >> 6, k = idx & 63;
    WlS[k * HID + j] = Wl[idx];
    WrS[k * HID + j] = Wr[idx];
  }
  if (t < HID) bs[t] = bl[t];
  __syncthreads();

  int lane = t & 63;
  int wv = t >> 6;            // 0..7
  int r = lane >> 4;          // neighbor slot 0..3
  int c = lane & 15;          // float4 column 0..15
  const float4* x4 = (const float4*)xo;
  float* myrow = &rowS[wv][0];

  for (int it = 0; it < 4; ++it) {
    int n = (blockIdx.x * 8 + wv) * 4 + it;
    int rp0 = rowptr[n], rp1 = rowptr[n + 1];

    // root row: issue early so latency hides under the gather
    float4 root;
    if (r == 0) root = x4[(size_t)n * 16 + c];

    float4 a0 = {0.f, 0.f, 0.f, 0.f};
    float4 a1 = {0.f, 0.f, 0.f, 0.f};
    float4 a2 = {0.f, 0.f, 0.f, 0.f};
    float4 a3 = {0.f, 0.f, 0.f, 0.f};
    int base = rp0;
    for (; base + 16 <= rp1; base += 16) {
      int s0 = col[base + r];
      int s1 = col[base + 4 + r];
      int s2 = col[base + 8 + r];
      int s3 = col[base + 12 + r];
      float4 v0 = x4[(size_t)s0 * 16 + c];
      float4 v1 = x4[(size_t)s1 * 16 + c];
      float4 v2 = x4[(size_t)s2 * 16 + c];
      float4 v3 = x4[(size_t)s3 * 16 + c];
      a0.x += v0.x; a0.y += v0.y; a0.z += v0.z; a0.w += v0.w;
      a1.x += v1.x; a1.y += v1.y; a1.z += v1.z; a1.w += v1.w;
      a2.x += v2.x; a2.y += v2.y; a2.z += v2.z; a2.w += v2.w;
      a3.x += v3.x; a3.y += v3.y; a3.z += v3.z; a3.w += v3.w;
    }
    if (base + 4 <= rp1) {
      int s0 = col[base + r];
      float4 v0 = x4[(size_t)s0 * 16 + c];
      a0.x += v0.x; a0.y += v0.y; a0.z += v0.z; a0.w += v0.w;
      base += 4;
    }
    if (base + 4 <= rp1) {
      int s1 = col[base + r];
      float4 v1 = x4[(size_t)s1 * 16 + c];
      a1.x += v1.x; a1.y += v1.y; a1.z += v1.z; a1.w += v1.w;
      base += 4;
    }
    if (base + 4 <= rp1) {
      int s2 = col[base + r];
      float4 v2 = x4[(size_t)s2 * 16 + c];
      a2.x += v2.x; a2.y += v2.y; a2.z += v2.z; a2.w += v2.w;
      base += 4;
    }
    if (base + r < rp1) {
      int s3 = col[base + r];
      float4 v3 = x4[(size_t)s3 * 16 + c];
      a3.x += v3.x; a3.y += v3.y; a3.z += v3.z; a3.w += v3.w;
    }
    float4 a;
    a.x = (a0.x + a1.x) + (a2.x + a3.x);
    a.y = (a0.y + a1.y) + (a2.y + a3.y);
    a.z = (a0.z + a1.z) + (a2.z + a3.z);
    a.w = (a0.w + a1.w) + (a2.w + a3.w);
    a.x += __shfl_xor(a.x, 16); a.y += __shfl_xor(a.y, 16);
    a.z += __shfl_xor(a.z, 16); a.w += __shfl_xor(a.w, 16);
    a.x += __shfl_xor(a.x, 32); a.y += __shfl_xor(a.y, 32);
    a.z += __shfl_xor(a.z, 32); a.w += __shfl_xor(a.w, 32);

    // park mean'd agg row + root row in wave-private LDS (no barrier needed)
    if (r == 0) {
      float id = 1.0f / (float)max(rp1 - rp0, 1);
      float4 o;
      o.x = a.x * id; o.y = a.y * id; o.z = a.z * id; o.w = a.w * id;
      ((float4*)myrow)[c] = o;
      ((float4*)myrow)[16 + c] = root;
    }

    // update: lane = output feature j
    float acc = bs[lane];
#pragma unroll 8
    for (int k = 0; k < HID; ++k) {
      acc += myrow[k] * WlS[k * HID + lane]
           + myrow[HID + k] * WrS[k * HID + lane];
    }
    xn[(size_t)n * HID + lane] = fmaxf(acc, 0.f);
  }
}

// ---------------------------------------------------------------------------
extern "C" void kernel_launch(void* const* d_in, const int* in_sizes, int n_in,
                              void* d_out, int out_size, void* d_ws, size_t ws_size,
                              hipStream_t stream) {
  const float* track_x  = (const float*)d_in[0];
  const int*   pl_tr_s  = (const int*)d_in[1];
  const int*   pl_tr_d  = (const int*)d_in[2];
  const int*   tr_ar_s  = (const int*)d_in[3];
  const int*   tr_ar_d  = (const int*)d_in[4];
  const float* pl_emb   = (const float*)d_in[5];
  const float* ar_emb   = (const float*)d_in[6];
  const float* track_W  = (const float*)d_in[7];
  const float* track_b  = (const float*)d_in[8];
  const float* type_emb = (const float*)d_in[9];
  const float* conv_Wl  = (const float*)d_in[10];
  const float* conv_bl  = (const float*)d_in[11];
  const float* conv_Wr  = (const float*)d_in[12];

  float* x = (float*)d_out;                      // node state (NN*64)

  // workspace: xalt ALIASES [pkd|tab] -- pkd/tab are dead once k_fill3 has
  // produced rowptr+col; xalt is first written by the layer-0 fused kernel
  // (stream-ordered after fill3). Total: 40.96 (xalt region, covers pkd
  // 16.81 + tab 1.29) + col 16.8 + rowptr 0.64 + btot 4KB = ~58.4 MB.
  char* w = (char*)d_ws;
  float* xalt   = (float*)w;
  int*   pkd    = (int*)w;
  int*   tab    = (int*)(w + (size_t)PKD_CAP * 4);
  w += (size_t)NN * HID * 4;
  int*   col    = (int*)w;    w += (size_t)E_TOT * 4;
  int*   rowptr = (int*)w;    w += (size_t)(NN + 1) * 4;
  int*   btot   = (int*)w;    // NBUCK ints

  k_init_emb<<<(NUM_PL + NUM_AR) * HID / 256, 256, 0, stream>>>(
      pl_emb, ar_emb, type_emb, x);
  k_track_lin<<<NUM_TR / 32, 256, 0, stream>>>(
      track_x, track_W, track_b, type_emb, x);

  // CSR build: bin -> bucket totals -> bucket scan -> count+scan+fill
  k_bin<<<NBLK_BIN, 256, 0, stream>>>(
      pl_tr_s, pl_tr_d, tr_ar_s, tr_ar_d, pkd, tab);
  k_btot<<<(NBUCK + 255) / 256, 256, 0, stream>>>(tab, btot);
  k_bscan<<<1, 1024, 0, stream>>>(btot);
  k_fill3<<<NBUCK, 256, 0, stream>>>(tab, pkd, btot, rowptr, col);

  // fused gather+update, ping-pong x <-> xalt (2 layers -> ends in x=d_out)
  k_gather_update<<<NN / 32, 512, 0, stream>>>(
      rowptr, col, x, conv_Wl, conv_bl, conv_Wr, xalt);
  k_gather_update<<<NN / 32, 512, 0, stream>>>(
      rowptr, col, xalt, conv_Wl + HID * HID, conv_bl + HID,
      conv_Wr + HID * HID, x);
}